// Round 3
// baseline (3542.473 us; speedup 1.0000x reference)
//
#include <hip/hip_runtime.h>
#include <math.h>

// ---------------------------------------------------------------------------
// Shapes: T=128, N=32 -> TN=4096
//  x: (4096,4,64,64) f32 | conv1 (32,4,8,8)s4 -> a1 (4096,32,15,15)
//  conv2 (64,32,4,4)s2 -> a2 (4096,64,6,6) | conv3 (64,64,3,3)s1 -> a3 (4096,1024)
//  fc (512,1024) -> feats (4096,512) | lstm wi(1024,512) wh(1024,256) H=256
//  heads: actor(18,256) critic(1,256) -> out (4096,19)
// ---------------------------------------------------------------------------

__device__ inline float dot8(float4 a, float4 b, float4 wa, float4 wb, float s) {
  s = fmaf(a.x, wa.x, s); s = fmaf(a.y, wa.y, s);
  s = fmaf(a.z, wa.z, s); s = fmaf(a.w, wa.w, s);
  s = fmaf(b.x, wb.x, s); s = fmaf(b.y, wb.y, s);
  s = fmaf(b.z, wb.z, s); s = fmaf(b.w, wb.w, s);
  return s;
}

// ---- conv1 v3: block = frame; x staged one channel at a time into LDS
// (row stride 68 -> 4 oy rows hit distinct bank groups; 16-lane broadcast free).
__global__ __launch_bounds__(256) void conv1_kernel(
    const float* __restrict__ x, const float* __restrict__ w,
    const float* __restrict__ bias, float* __restrict__ out) {
  __shared__ float xs[64 * 68];      // 17408 B, one input channel
  const int n = blockIdx.x;
  const int t = threadIdx.x;
  const int oy = t >> 4;             // 0..15 (15 idle in compute)
  const int og = t & 15;
  const int oc0 = og * 2;

  float acc[15][2] = {};
  const float4* xg = (const float4*)(x + (size_t)n * 16384);
  const float* wb = w + oc0 * 256;   // oc stride 4*8*8=256

  for (int c = 0; c < 4; ++c) {
    __syncthreads();                 // previous channel consumed
    #pragma unroll
    for (int i = 0; i < 4; ++i) {    // stage 1024 float4
      int f4 = i * 256 + t;
      int y = f4 >> 4, xq = f4 & 15;
      *(float4*)&xs[y * 68 + xq * 4] = xg[c * 1024 + f4];
    }
    __syncthreads();
    if (oy < 15) {
      for (int ky = 0; ky < 8; ++ky) {
        const float* xr = &xs[(4 * oy + ky) * 68];
        const float* wr = wb + c * 64 + ky * 8;
        const float4 w00 = *(const float4*)(wr);
        const float4 w01 = *(const float4*)(wr + 4);
        const float4 w10 = *(const float4*)(wr + 256);
        const float4 w11 = *(const float4*)(wr + 260);
        {
          float4 xv[9];
          #pragma unroll
          for (int i = 0; i < 9; ++i) xv[i] = *(const float4*)(xr + 4 * i);
          #pragma unroll
          for (int p = 0; p < 8; ++p) {
            acc[p][0] = dot8(xv[p], xv[p + 1], w00, w01, acc[p][0]);
            acc[p][1] = dot8(xv[p], xv[p + 1], w10, w11, acc[p][1]);
          }
        }
        {
          float4 yv[8];
          #pragma unroll
          for (int i = 0; i < 8; ++i) yv[i] = *(const float4*)(xr + 32 + 4 * i);
          #pragma unroll
          for (int p = 8; p < 15; ++p) {
            acc[p][0] = dot8(yv[p - 8], yv[p - 7], w00, w01, acc[p][0]);
            acc[p][1] = dot8(yv[p - 8], yv[p - 7], w10, w11, acc[p][1]);
          }
        }
      }
    }
  }
  if (oy < 15) {
    const float inv = 1.f / 255.f;
    #pragma unroll
    for (int o = 0; o < 2; ++o) {
      const int oc = oc0 + o;
      const float bb = bias[oc];
      float* orow = out + ((size_t)n * 32 + oc) * 225 + oy * 15;
      #pragma unroll
      for (int p = 0; p < 15; ++p)
        orow[p] = fmaxf(fmaf(acc[p][o], inv, bb), 0.f);
    }
  }
}

// ---- conv2 v3: block = frame (192 thr); a1 frame staged in LDS, rows padded
// to 16 floats (float4-aligned); reads are 2-address broadcasts (free).
__global__ __launch_bounds__(192) void conv2_kernel(
    const float* __restrict__ a1, const float* __restrict__ w,
    const float* __restrict__ bias, float* __restrict__ out) {
  __shared__ float xs[32 * 15 * 16];   // 30720 B
  const int n = blockIdx.x;
  const int t = threadIdx.x;           // 0..191
  const float* ag = a1 + (size_t)n * 7200;
  for (int i = 0; i < 38; ++i) {
    int idx = i * 192 + t;
    if (idx < 7200) {
      int c = idx / 225, rem = idx - c * 225;
      int row = rem / 15, col = rem - row * 15;
      xs[(c * 15 + row) * 16 + col] = ag[idx];
    }
  }
  __syncthreads();

  const int oy = t >> 5;               // 0..5
  const int op = t & 31;
  const int oc0 = op * 2;
  float acc[6][2] = {};
  const float* wb = w + oc0 * 512;     // oc stride 32*4*4=512

  for (int c = 0; c < 32; ++c) {
    #pragma unroll
    for (int ky = 0; ky < 4; ++ky) {
      const float* xr = &xs[(c * 15 + 2 * oy + ky) * 16];
      const float4 xa = *(const float4*)(xr);
      const float4 xb = *(const float4*)(xr + 4);
      const float4 xc = *(const float4*)(xr + 8);
      const float2 xd = *(const float2*)(xr + 12);
      const float xv[14] = {xa.x, xa.y, xa.z, xa.w, xb.x, xb.y, xb.z, xb.w,
                            xc.x, xc.y, xc.z, xc.w, xd.x, xd.y};
      const float* wr = wb + c * 16 + ky * 4;
      const float4 w0 = *(const float4*)(wr);
      const float4 w1 = *(const float4*)(wr + 512);
      #pragma unroll
      for (int p = 0; p < 6; ++p) {
        const int b = 2 * p;
        float s0 = acc[p][0], s1 = acc[p][1];
        s0 = fmaf(xv[b], w0.x, s0);     s1 = fmaf(xv[b], w1.x, s1);
        s0 = fmaf(xv[b + 1], w0.y, s0); s1 = fmaf(xv[b + 1], w1.y, s1);
        s0 = fmaf(xv[b + 2], w0.z, s0); s1 = fmaf(xv[b + 2], w1.z, s1);
        s0 = fmaf(xv[b + 3], w0.w, s0); s1 = fmaf(xv[b + 3], w1.w, s1);
        acc[p][0] = s0; acc[p][1] = s1;
      }
    }
  }
  #pragma unroll
  for (int o = 0; o < 2; ++o) {
    const int oc = oc0 + o;
    const float bb = bias[oc];
    float* orow = out + ((size_t)n * 64 + oc) * 36 + oy * 6;
    #pragma unroll
    for (int p = 0; p < 6; ++p)
      orow[p] = fmaxf(acc[p][o] + bb, 0.f);
  }
}

// ---- conv3 v3: block = frame; x frame AND transposed weights in LDS ----
__global__ __launch_bounds__(256) void conv3_kernel(
    const float* __restrict__ a2, const float* __restrict__ w,
    const float* __restrict__ bias, float* __restrict__ out) {
  __shared__ float wTs[144 * 65];      // 37440 B
  __shared__ float xs2[64 * 36];       // 9216 B
  const int n = blockIdx.x;
  const int t = threadIdx.x;
  const int oy = t >> 6;               // 0..3
  const int oc = t & 63;

  const float* ab = a2 + (size_t)n * 2304;
  #pragma unroll
  for (int i = 0; i < 9; ++i) xs2[i * 256 + t] = ab[i * 256 + t];

  float acc[4] = {};
  for (int c0 = 0; c0 < 64; c0 += 16) {
    __syncthreads();
    #pragma unroll
    for (int i = 0; i < 36; ++i) {
      const int lin = i * 256 + t;
      const int ocs = lin / 144;
      const int rem = lin - ocs * 144;
      wTs[rem * 65 + ocs] = w[(size_t)ocs * 576 + c0 * 9 + rem];
    }
    __syncthreads();
    for (int cc = 0; cc < 16; ++cc) {
      const float* xb = &xs2[(c0 + cc) * 36];
      #pragma unroll
      for (int ky = 0; ky < 3; ++ky) {
        const float* xr = xb + (oy + ky) * 6;
        const float2 x01 = *(const float2*)(xr);
        const float2 x23 = *(const float2*)(xr + 2);
        const float2 x45 = *(const float2*)(xr + 4);
        const float xv[6] = {x01.x, x01.y, x23.x, x23.y, x45.x, x45.y};
        const float* wrow = &wTs[(cc * 9 + ky * 3) * 65 + oc];
        const float wk0 = wrow[0], wk1 = wrow[65], wk2 = wrow[130];
        #pragma unroll
        for (int p = 0; p < 4; ++p)
          acc[p] = fmaf(xv[p], wk0,
                   fmaf(xv[p + 1], wk1,
                   fmaf(xv[p + 2], wk2, acc[p])));
      }
    }
  }
  const float bb = bias[oc];
  float* orow = out + ((size_t)n * 64 + oc) * 16 + oy * 4;
  #pragma unroll
  for (int p = 0; p < 4; ++p)
    orow[p] = fmaxf(acc[p] + bb, 0.f);
}

// ---- generic GEMM: C[M,N] = act(A[M,K] @ B[N,K]^T + bias1 (+bias2)) ----
__global__ __launch_bounds__(256) void gemm_bias_kernel(
    const float* __restrict__ A, const float* __restrict__ B,
    const float* __restrict__ bias1, const float* __restrict__ bias2,
    float* __restrict__ C, int M, int N, int K, int relu) {
  __shared__ float As[16][68];
  __shared__ float Bs[16][68];
  const int t = threadIdx.x;
  const int n0 = blockIdx.x * 64;
  const int m0 = blockIdx.y * 64;
  const int ty = t >> 4, tx = t & 15;
  const int sl = t >> 2, kq = (t & 3) * 4;

  float acc[4][4] = {};

  for (int k0 = 0; k0 < K; k0 += 16) {
    float4 av = *(const float4*)(A + (size_t)(m0 + sl) * K + k0 + kq);
    float4 bv = *(const float4*)(B + (size_t)(n0 + sl) * K + k0 + kq);
    As[kq + 0][sl] = av.x; As[kq + 1][sl] = av.y;
    As[kq + 2][sl] = av.z; As[kq + 3][sl] = av.w;
    Bs[kq + 0][sl] = bv.x; Bs[kq + 1][sl] = bv.y;
    Bs[kq + 2][sl] = bv.z; Bs[kq + 3][sl] = bv.w;
    __syncthreads();
    #pragma unroll
    for (int kk = 0; kk < 16; ++kk) {
      float4 a = *(const float4*)&As[kk][ty * 4];
      float4 b = *(const float4*)&Bs[kk][tx * 4];
      float ar[4] = {a.x, a.y, a.z, a.w};
      float br[4] = {b.x, b.y, b.z, b.w};
      #pragma unroll
      for (int i = 0; i < 4; ++i)
        #pragma unroll
        for (int j = 0; j < 4; ++j)
          acc[i][j] = fmaf(ar[i], br[j], acc[i][j]);
    }
    __syncthreads();
  }

  #pragma unroll
  for (int i = 0; i < 4; ++i) {
    int m = m0 + ty * 4 + i;
    #pragma unroll
    for (int j = 0; j < 4; ++j) {
      int n = n0 + tx * 4 + j;
      float v = acc[i][j] + bias1[n];
      if (bias2) v += bias2[n];
      if (relu) v = fmaxf(v, 0.f);
      C[(size_t)m * N + n] = v;
    }
  }
}

// ---- persistent LSTM: 128 blocks x 256 thr, all co-resident (<=256 CUs).
// Block bk owns j in {2bk,2bk+1} for all 32 envs; c lives in LDS; h exchanged
// via outs[] with agent-scope atomics; per-step counter barrier in ws (G16).
#define LSTM_NBLK 128
__global__ __launch_bounds__(256) void lstm_persist_kernel(
    const float* __restrict__ gates_pre, const float* __restrict__ wh,
    const float* __restrict__ done, const float* __restrict__ h0,
    const float* __restrict__ c0, float* __restrict__ outs,
    unsigned int* __restrict__ ctr) {
  __shared__ float hs[256 * 33];   // hs[k*33+b] = masked h_prev[b][k]
  __shared__ float wh_s[256 * 8];  // wh_s[k*8 + jj*4 + g]
  __shared__ float red[256 * 8];   // partial dots [t][eb*4+g]
  __shared__ float gb[256];        // gates [g*64 + jj*32 + b]
  __shared__ float c_s[64];        // c [jj*32 + b]
  const int t = threadIdx.x;
  const int bk = blockIdx.x;

  for (int i = 0; i < 8; ++i) {    // stage this block's 8 wh rows (once)
    int lin = i * 256 + t;
    int k = lin >> 3, idx = lin & 7;
    int jj = idx >> 2, g = idx & 3;
    wh_s[lin] = wh[(size_t)(g * 256 + 2 * bk + jj) * 256 + k];
  }
  if (t < 64) {
    int b = t & 31, jj = t >> 5;
    c_s[t] = c0[b * 256 + 2 * bk + jj];
  }
  const int bq = t & 15;           // env pair: b0=2bq, b1=2bq+1
  const int ks = (t >> 4) & 7;     // k-split slot (k = i*8+ks)
  const int jjd = t >> 7;
  __syncthreads();

  for (int st = 0; st < 128; ++st) {
    // stage masked h_prev: hs[t*33 + i] = h_prev[i][t] * m[i]
    const float* hp = (st == 0) ? h0 : (outs + (size_t)(st - 1) * 8192);
    for (int i = 0; i < 32; ++i) {
      float m = 1.f - done[st * 32 + i];
      float hv = __hip_atomic_load((const float*)(hp + i * 256 + t),
                                   __ATOMIC_RELAXED, __HIP_MEMORY_SCOPE_AGENT);
      hs[t * 33 + i] = hv * m;
    }
    __syncthreads();

    // partial dots: 2 envs x 4 gates, interleaved k for bank-friendliness
    float a0x = 0, a0y = 0, a0z = 0, a0w = 0;
    float a1x = 0, a1y = 0, a1z = 0, a1w = 0;
    #pragma unroll 8
    for (int i = 0; i < 32; ++i) {
      int k = i * 8 + ks;
      float h0v = hs[k * 33 + 2 * bq];
      float h1v = hs[k * 33 + 2 * bq + 1];
      float4 wv = *(const float4*)&wh_s[k * 8 + jjd * 4];
      a0x = fmaf(h0v, wv.x, a0x); a0y = fmaf(h0v, wv.y, a0y);
      a0z = fmaf(h0v, wv.z, a0z); a0w = fmaf(h0v, wv.w, a0w);
      a1x = fmaf(h1v, wv.x, a1x); a1y = fmaf(h1v, wv.y, a1y);
      a1z = fmaf(h1v, wv.z, a1z); a1w = fmaf(h1v, wv.w, a1w);
    }
    red[t * 8 + 0] = a0x; red[t * 8 + 1] = a0y;
    red[t * 8 + 2] = a0z; red[t * 8 + 3] = a0w;
    red[t * 8 + 4] = a1x; red[t * 8 + 5] = a1y;
    red[t * 8 + 6] = a1z; red[t * 8 + 7] = a1w;
    __syncthreads();

    // finalize one gate per thread: t -> (b, g, jj)
    {
      int b = t & 31, g = (t >> 5) & 3, jj = t >> 7;
      int bq2 = b >> 1, eb = b & 1;
      float s = 0.f;
      #pragma unroll
      for (int k8 = 0; k8 < 8; ++k8)
        s += red[(jj * 128 + k8 * 16 + bq2) * 8 + eb * 4 + g];
      s += gates_pre[(size_t)(st * 32 + b) * 1024 + g * 256 + 2 * bk + jj];
      gb[g * 64 + jj * 32 + b] = s;
    }
    __syncthreads();

    if (t < 64) {
      int b = t & 31, jj = t >> 5;
      int j = 2 * bk + jj;
      float iv = gb[0   + jj * 32 + b];
      float fv = gb[64  + jj * 32 + b];
      float gv = gb[128 + jj * 32 + b];
      float ov = gb[192 + jj * 32 + b];
      float m = 1.f - done[st * 32 + b];
      float c_old = c_s[jj * 32 + b] * m;
      float ig = 1.f / (1.f + expf(-iv));
      float fg = 1.f / (1.f + expf(-fv));
      float og = 1.f / (1.f + expf(-ov));
      float cn = fmaf(fg, c_old, ig * tanhf(gv));
      float hn = og * tanhf(cn);
      c_s[jj * 32 + b] = cn;
      __hip_atomic_store(outs + (size_t)st * 8192 + b * 256 + j, hn,
                         __ATOMIC_RELAXED, __HIP_MEMORY_SCOPE_AGENT);
    }
    __syncthreads();   // gb/c_s consumed; h stores issued (waitcnt at barrier)

    if (st < 127) {    // grid barrier before next step reads outs[st]
      if (t == 0) {
        __threadfence();   // release (agent): flush block's h stores
        __hip_atomic_fetch_add(&ctr[st], 1u, __ATOMIC_RELEASE,
                               __HIP_MEMORY_SCOPE_AGENT);
        while (__hip_atomic_load(&ctr[st], __ATOMIC_ACQUIRE,
                                 __HIP_MEMORY_SCOPE_AGENT) < LSTM_NBLK)
          __builtin_amdgcn_s_sleep(2);
        __threadfence();   // acquire: invalidate stale caches
      }
      __syncthreads();
    }
  }
}

// ---- heads ----
__global__ __launch_bounds__(256) void heads_kernel(
    const float* __restrict__ outs, const float* __restrict__ aw,
    const float* __restrict__ ab, const float* __restrict__ cw,
    const float* __restrict__ cb, float* __restrict__ out) {
  __shared__ float rs[8 * 256];
  const int t = threadIdx.x;
  const int r0 = blockIdx.x * 8;
  for (int i = 0; i < 8; ++i)
    rs[i * 256 + t] = outs[(size_t)(r0 + i) * 256 + t];
  __syncthreads();
  int r = t >> 5, c = t & 31;
  if (c < 19) {
    const float* wr = (c < 18) ? (aw + c * 256) : cw;
    float bias = (c < 18) ? ab[c] : cb[0];
    float acc = 0.f;
    for (int k = 0; k < 256; ++k) acc = fmaf(rs[r * 256 + k], wr[k], acc);
    out[(size_t)(r0 + r) * 19 + c] = acc + bias;
  }
}

extern "C" void kernel_launch(void* const* d_in, const int* in_sizes, int n_in,
                              void* d_out, int out_size, void* d_ws, size_t ws_size,
                              hipStream_t stream) {
  (void)in_sizes; (void)n_in; (void)out_size;
  const float* x    = (const float*)d_in[0];
  const float* done = (const float*)d_in[1];
  const float* h0   = (const float*)d_in[2];
  const float* c0   = (const float*)d_in[3];
  const float* w1   = (const float*)d_in[4];
  const float* b1   = (const float*)d_in[5];
  const float* w2   = (const float*)d_in[6];
  const float* b2   = (const float*)d_in[7];
  const float* w3   = (const float*)d_in[8];
  const float* b3   = (const float*)d_in[9];
  const float* fcw  = (const float*)d_in[10];
  const float* fcb  = (const float*)d_in[11];
  const float* wi   = (const float*)d_in[12];
  const float* wh   = (const float*)d_in[13];
  const float* bi   = (const float*)d_in[14];
  const float* bh   = (const float*)d_in[15];
  const float* aw   = (const float*)d_in[16];
  const float* abv  = (const float*)d_in[17];
  const float* cw   = (const float*)d_in[18];
  const float* cbv  = (const float*)d_in[19];
  float* out = (float*)d_out;

  const size_t SZ_A1 = 29491200, SZ_A2 = 9437184, SZ_A3 = 4194304;
  const size_t SZ_F = 2097152, SZ_G = 4194304, SZ_O = 1048576;
  const size_t need = (SZ_A1 + SZ_A2 + SZ_A3 + SZ_F + SZ_G + SZ_O) * 4 + 512;
  if (ws_size < need) return;

  float* wsp  = (float*)d_ws;
  float* a1   = wsp;
  float* a2   = a1 + SZ_A1;
  float* a3   = a2 + SZ_A2;
  float* feats= a3 + SZ_A3;
  float* gts  = feats + SZ_F;
  float* outs = gts + SZ_G;
  unsigned int* ctr = (unsigned int*)(outs + SZ_O);

  conv1_kernel<<<4096, 256, 0, stream>>>(x, w1, b1, a1);
  conv2_kernel<<<4096, 192, 0, stream>>>(a1, w2, b2, a2);
  conv3_kernel<<<4096, 256, 0, stream>>>(a2, w3, b3, a3);
  gemm_bias_kernel<<<dim3(8, 64), 256, 0, stream>>>(a3, fcw, fcb, nullptr, feats,
                                                    4096, 512, 1024, 1);
  gemm_bias_kernel<<<dim3(16, 64), 256, 0, stream>>>(feats, wi, bi, bh, gts,
                                                     4096, 1024, 512, 0);
  hipMemsetAsync(ctr, 0, 512, stream);
  lstm_persist_kernel<<<LSTM_NBLK, 256, 0, stream>>>(gts, wh, done, h0, c0,
                                                     outs, ctr);
  heads_kernel<<<512, 256, 0, stream>>>(outs, aw, abv, cw, cbv, out);
}

// Round 4
// 3340.846 us; speedup vs baseline: 1.0604x; 1.0604x over previous
//
#include <hip/hip_runtime.h>
#include <math.h>

// ---------------------------------------------------------------------------
// Shapes: T=128, N=32 -> TN=4096
//  x: (4096,4,64,64) f32 | conv1 (32,4,8,8)s4 -> a1 (4096,32,15,15)
//  conv2 (64,32,4,4)s2 -> a2 (4096,64,6,6) | conv3 (64,64,3,3)s1 -> a3 (4096,1024)
//  fc (512,1024) -> feats (4096,512) | lstm wi(1024,512) wh(1024,256) H=256
//  heads: actor(18,256) critic(1,256) -> out (4096,19)
// ---------------------------------------------------------------------------

__device__ inline float dot8(float4 a, float4 b, float4 wa, float4 wb, float s) {
  s = fmaf(a.x, wa.x, s); s = fmaf(a.y, wa.y, s);
  s = fmaf(a.z, wa.z, s); s = fmaf(a.w, wa.w, s);
  s = fmaf(b.x, wb.x, s); s = fmaf(b.y, wb.y, s);
  s = fmaf(b.z, wb.z, s); s = fmaf(b.w, wb.w, s);
  return s;
}

// ---- conv1 v3: block = frame; x staged one channel at a time into LDS ----
__global__ __launch_bounds__(256) void conv1_kernel(
    const float* __restrict__ x, const float* __restrict__ w,
    const float* __restrict__ bias, float* __restrict__ out) {
  __shared__ float xs[64 * 68];      // 17408 B, one input channel
  const int n = blockIdx.x;
  const int t = threadIdx.x;
  const int oy = t >> 4;             // 0..15 (15 idle in compute)
  const int og = t & 15;
  const int oc0 = og * 2;

  float acc[15][2] = {};
  const float4* xg = (const float4*)(x + (size_t)n * 16384);
  const float* wb = w + oc0 * 256;   // oc stride 4*8*8=256

  for (int c = 0; c < 4; ++c) {
    __syncthreads();                 // previous channel consumed
    #pragma unroll
    for (int i = 0; i < 4; ++i) {    // stage 1024 float4
      int f4 = i * 256 + t;
      int y = f4 >> 4, xq = f4 & 15;
      *(float4*)&xs[y * 68 + xq * 4] = xg[c * 1024 + f4];
    }
    __syncthreads();
    if (oy < 15) {
      for (int ky = 0; ky < 8; ++ky) {
        const float* xr = &xs[(4 * oy + ky) * 68];
        const float* wr = wb + c * 64 + ky * 8;
        const float4 w00 = *(const float4*)(wr);
        const float4 w01 = *(const float4*)(wr + 4);
        const float4 w10 = *(const float4*)(wr + 256);
        const float4 w11 = *(const float4*)(wr + 260);
        {
          float4 xv[9];
          #pragma unroll
          for (int i = 0; i < 9; ++i) xv[i] = *(const float4*)(xr + 4 * i);
          #pragma unroll
          for (int p = 0; p < 8; ++p) {
            acc[p][0] = dot8(xv[p], xv[p + 1], w00, w01, acc[p][0]);
            acc[p][1] = dot8(xv[p], xv[p + 1], w10, w11, acc[p][1]);
          }
        }
        {
          float4 yv[8];
          #pragma unroll
          for (int i = 0; i < 8; ++i) yv[i] = *(const float4*)(xr + 32 + 4 * i);
          #pragma unroll
          for (int p = 8; p < 15; ++p) {
            acc[p][0] = dot8(yv[p - 8], yv[p - 7], w00, w01, acc[p][0]);
            acc[p][1] = dot8(yv[p - 8], yv[p - 7], w10, w11, acc[p][1]);
          }
        }
      }
    }
  }
  if (oy < 15) {
    const float inv = 1.f / 255.f;
    #pragma unroll
    for (int o = 0; o < 2; ++o) {
      const int oc = oc0 + o;
      const float bb = bias[oc];
      float* orow = out + ((size_t)n * 32 + oc) * 225 + oy * 15;
      #pragma unroll
      for (int p = 0; p < 15; ++p)
        orow[p] = fmaxf(fmaf(acc[p][o], inv, bb), 0.f);
    }
  }
}

// ---- conv2 v3: block = frame (192 thr); a1 frame staged in LDS ----
__global__ __launch_bounds__(192) void conv2_kernel(
    const float* __restrict__ a1, const float* __restrict__ w,
    const float* __restrict__ bias, float* __restrict__ out) {
  __shared__ float xs[32 * 15 * 16];   // 30720 B
  const int n = blockIdx.x;
  const int t = threadIdx.x;           // 0..191
  const float* ag = a1 + (size_t)n * 7200;
  for (int i = 0; i < 38; ++i) {
    int idx = i * 192 + t;
    if (idx < 7200) {
      int c = idx / 225, rem = idx - c * 225;
      int row = rem / 15, col = rem - row * 15;
      xs[(c * 15 + row) * 16 + col] = ag[idx];
    }
  }
  __syncthreads();

  const int oy = t >> 5;               // 0..5
  const int op = t & 31;
  const int oc0 = op * 2;
  float acc[6][2] = {};
  const float* wb = w + oc0 * 512;     // oc stride 32*4*4=512

  for (int c = 0; c < 32; ++c) {
    #pragma unroll
    for (int ky = 0; ky < 4; ++ky) {
      const float* xr = &xs[(c * 15 + 2 * oy + ky) * 16];
      const float4 xa = *(const float4*)(xr);
      const float4 xb = *(const float4*)(xr + 4);
      const float4 xc = *(const float4*)(xr + 8);
      const float2 xd = *(const float2*)(xr + 12);
      const float xv[14] = {xa.x, xa.y, xa.z, xa.w, xb.x, xb.y, xb.z, xb.w,
                            xc.x, xc.y, xc.z, xc.w, xd.x, xd.y};
      const float* wr = wb + c * 16 + ky * 4;
      const float4 w0 = *(const float4*)(wr);
      const float4 w1 = *(const float4*)(wr + 512);
      #pragma unroll
      for (int p = 0; p < 6; ++p) {
        const int b = 2 * p;
        float s0 = acc[p][0], s1 = acc[p][1];
        s0 = fmaf(xv[b], w0.x, s0);     s1 = fmaf(xv[b], w1.x, s1);
        s0 = fmaf(xv[b + 1], w0.y, s0); s1 = fmaf(xv[b + 1], w1.y, s1);
        s0 = fmaf(xv[b + 2], w0.z, s0); s1 = fmaf(xv[b + 2], w1.z, s1);
        s0 = fmaf(xv[b + 3], w0.w, s0); s1 = fmaf(xv[b + 3], w1.w, s1);
        acc[p][0] = s0; acc[p][1] = s1;
      }
    }
  }
  #pragma unroll
  for (int o = 0; o < 2; ++o) {
    const int oc = oc0 + o;
    const float bb = bias[oc];
    float* orow = out + ((size_t)n * 64 + oc) * 36 + oy * 6;
    #pragma unroll
    for (int p = 0; p < 6; ++p)
      orow[p] = fmaxf(acc[p][o] + bb, 0.f);
  }
}

// ---- conv3 v3: block = frame; x frame AND transposed weights in LDS ----
__global__ __launch_bounds__(256) void conv3_kernel(
    const float* __restrict__ a2, const float* __restrict__ w,
    const float* __restrict__ bias, float* __restrict__ out) {
  __shared__ float wTs[144 * 65];      // 37440 B
  __shared__ float xs2[64 * 36];       // 9216 B
  const int n = blockIdx.x;
  const int t = threadIdx.x;
  const int oy = t >> 6;               // 0..3
  const int oc = t & 63;

  const float* ab = a2 + (size_t)n * 2304;
  #pragma unroll
  for (int i = 0; i < 9; ++i) xs2[i * 256 + t] = ab[i * 256 + t];

  float acc[4] = {};
  for (int c0 = 0; c0 < 64; c0 += 16) {
    __syncthreads();
    #pragma unroll
    for (int i = 0; i < 36; ++i) {
      const int lin = i * 256 + t;
      const int ocs = lin / 144;
      const int rem = lin - ocs * 144;
      wTs[rem * 65 + ocs] = w[(size_t)ocs * 576 + c0 * 9 + rem];
    }
    __syncthreads();
    for (int cc = 0; cc < 16; ++cc) {
      const float* xb = &xs2[(c0 + cc) * 36];
      #pragma unroll
      for (int ky = 0; ky < 3; ++ky) {
        const float* xr = xb + (oy + ky) * 6;
        const float2 x01 = *(const float2*)(xr);
        const float2 x23 = *(const float2*)(xr + 2);
        const float2 x45 = *(const float2*)(xr + 4);
        const float xv[6] = {x01.x, x01.y, x23.x, x23.y, x45.x, x45.y};
        const float* wrow = &wTs[(cc * 9 + ky * 3) * 65 + oc];
        const float wk0 = wrow[0], wk1 = wrow[65], wk2 = wrow[130];
        #pragma unroll
        for (int p = 0; p < 4; ++p)
          acc[p] = fmaf(xv[p], wk0,
                   fmaf(xv[p + 1], wk1,
                   fmaf(xv[p + 2], wk2, acc[p])));
      }
    }
  }
  const float bb = bias[oc];
  float* orow = out + ((size_t)n * 64 + oc) * 16 + oy * 4;
  #pragma unroll
  for (int p = 0; p < 4; ++p)
    orow[p] = fmaxf(acc[p] + bb, 0.f);
}

// ---- generic GEMM: C[M,N] = act(A[M,K] @ B[N,K]^T + bias1 (+bias2)) ----
__global__ __launch_bounds__(256) void gemm_bias_kernel(
    const float* __restrict__ A, const float* __restrict__ B,
    const float* __restrict__ bias1, const float* __restrict__ bias2,
    float* __restrict__ C, int M, int N, int K, int relu) {
  __shared__ float As[16][68];
  __shared__ float Bs[16][68];
  const int t = threadIdx.x;
  const int n0 = blockIdx.x * 64;
  const int m0 = blockIdx.y * 64;
  const int ty = t >> 4, tx = t & 15;
  const int sl = t >> 2, kq = (t & 3) * 4;

  float acc[4][4] = {};

  for (int k0 = 0; k0 < K; k0 += 16) {
    float4 av = *(const float4*)(A + (size_t)(m0 + sl) * K + k0 + kq);
    float4 bv = *(const float4*)(B + (size_t)(n0 + sl) * K + k0 + kq);
    As[kq + 0][sl] = av.x; As[kq + 1][sl] = av.y;
    As[kq + 2][sl] = av.z; As[kq + 3][sl] = av.w;
    Bs[kq + 0][sl] = bv.x; Bs[kq + 1][sl] = bv.y;
    Bs[kq + 2][sl] = bv.z; Bs[kq + 3][sl] = bv.w;
    __syncthreads();
    #pragma unroll
    for (int kk = 0; kk < 16; ++kk) {
      float4 a = *(const float4*)&As[kk][ty * 4];
      float4 b = *(const float4*)&Bs[kk][tx * 4];
      float ar[4] = {a.x, a.y, a.z, a.w};
      float br[4] = {b.x, b.y, b.z, b.w};
      #pragma unroll
      for (int i = 0; i < 4; ++i)
        #pragma unroll
        for (int j = 0; j < 4; ++j)
          acc[i][j] = fmaf(ar[i], br[j], acc[i][j]);
    }
    __syncthreads();
  }

  #pragma unroll
  for (int i = 0; i < 4; ++i) {
    int m = m0 + ty * 4 + i;
    #pragma unroll
    for (int j = 0; j < 4; ++j) {
      int n = n0 + tx * 4 + j;
      float v = acc[i][j] + bias1[n];
      if (bias2) v += bias2[n];
      if (relu) v = fmaxf(v, 0.f);
      C[(size_t)m * N + n] = v;
    }
  }
}

// ---- wh transpose: (1024,256) -> whT (256,1024), 32x32 LDS tiles ----
__global__ __launch_bounds__(256) void transpose_wh_kernel(
    const float* __restrict__ wh, float* __restrict__ whT) {
  __shared__ float tile[32][33];
  const int bx = blockIdx.x;           // row-block of wh (r), 0..31
  const int by = blockIdx.y;           // col-block (k), 0..7
  const int tx = threadIdx.x & 31;
  const int ty = threadIdx.x >> 5;     // 0..7
  #pragma unroll
  for (int i = 0; i < 4; ++i) {
    int r = bx * 32 + ty + i * 8;
    tile[ty + i * 8][tx] = wh[(size_t)r * 256 + by * 32 + tx];
  }
  __syncthreads();
  #pragma unroll
  for (int i = 0; i < 4; ++i) {
    int k = by * 32 + ty + i * 8;
    whT[(size_t)k * 1024 + bx * 32 + tx] = tile[tx][ty + i * 8];
  }
}

// ---- LSTM, env-parallel: block = one env, all 128 steps in-block.
// No inter-block communication at all (envs are independent through the
// recurrence; the gates_pre GEMM already handled the feats coupling).
// Thread t owns Wh rows 2t,2t+1; whT is k-major so lane loads coalesce.
__global__ __launch_bounds__(512) void lstm_env_kernel(
    const float* __restrict__ gates_pre, const float* __restrict__ whT,
    const float* __restrict__ done, const float* __restrict__ h0,
    const float* __restrict__ c0, float* __restrict__ outs) {
  __shared__ float h_s[256];
  __shared__ float c_s[256];
  __shared__ float gb[1024];
  const int e = blockIdx.x;            // env 0..31
  const int t = threadIdx.x;           // 0..511
  if (t < 256) {
    h_s[t] = h0[e * 256 + t];
    c_s[t] = c0[e * 256 + t];
  }
  __syncthreads();
  const int r0 = t * 2;

  for (int st = 0; st < 128; ++st) {
    const float m = 1.f - done[st * 32 + e];
    if (t < 256) { h_s[t] *= m; c_s[t] *= m; }
    __syncthreads();

    // dot over k: rows r0, r0+1 of Wh; whT[k][r] layout -> float2 coalesced
    float acc0 = 0.f, acc1 = 0.f;
    const float* wp = whT + r0;
    #pragma unroll 4
    for (int k = 0; k < 256; k += 4) {
      const float4 hv = *(const float4*)&h_s[k];   // ds_read_b128 broadcast
      const float2 w0 = *(const float2*)(wp + (size_t)(k + 0) * 1024);
      const float2 w1 = *(const float2*)(wp + (size_t)(k + 1) * 1024);
      const float2 w2 = *(const float2*)(wp + (size_t)(k + 2) * 1024);
      const float2 w3 = *(const float2*)(wp + (size_t)(k + 3) * 1024);
      acc0 = fmaf(hv.x, w0.x, acc0); acc1 = fmaf(hv.x, w0.y, acc1);
      acc0 = fmaf(hv.y, w1.x, acc0); acc1 = fmaf(hv.y, w1.y, acc1);
      acc0 = fmaf(hv.z, w2.x, acc0); acc1 = fmaf(hv.z, w2.y, acc1);
      acc0 = fmaf(hv.w, w3.x, acc0); acc1 = fmaf(hv.w, w3.y, acc1);
    }
    const float2 gp = *(const float2*)(gates_pre +
                       (size_t)(st * 32 + e) * 1024 + r0);
    *(float2*)&gb[r0] = make_float2(acc0 + gp.x, acc1 + gp.y);
    __syncthreads();

    if (t < 256) {
      float iv = gb[t], fv = gb[256 + t], gv = gb[512 + t], ov = gb[768 + t];
      float ig = 1.f / (1.f + expf(-iv));
      float fg = 1.f / (1.f + expf(-fv));
      float og = 1.f / (1.f + expf(-ov));
      float cn = fmaf(fg, c_s[t], ig * tanhf(gv));
      float hn = og * tanhf(cn);
      c_s[t] = cn;
      h_s[t] = hn;
      outs[(size_t)st * 8192 + e * 256 + t] = hn;
    }
    __syncthreads();
  }
}

// ---- heads ----
__global__ __launch_bounds__(256) void heads_kernel(
    const float* __restrict__ outs, const float* __restrict__ aw,
    const float* __restrict__ ab, const float* __restrict__ cw,
    const float* __restrict__ cb, float* __restrict__ out) {
  __shared__ float rs[8 * 256];
  const int t = threadIdx.x;
  const int r0 = blockIdx.x * 8;
  for (int i = 0; i < 8; ++i)
    rs[i * 256 + t] = outs[(size_t)(r0 + i) * 256 + t];
  __syncthreads();
  int r = t >> 5, c = t & 31;
  if (c < 19) {
    const float* wr = (c < 18) ? (aw + c * 256) : cw;
    float bias = (c < 18) ? ab[c] : cb[0];
    float acc = 0.f;
    for (int k = 0; k < 256; ++k) acc = fmaf(rs[r * 256 + k], wr[k], acc);
    out[(size_t)(r0 + r) * 19 + c] = acc + bias;
  }
}

extern "C" void kernel_launch(void* const* d_in, const int* in_sizes, int n_in,
                              void* d_out, int out_size, void* d_ws, size_t ws_size,
                              hipStream_t stream) {
  (void)in_sizes; (void)n_in; (void)out_size;
  const float* x    = (const float*)d_in[0];
  const float* done = (const float*)d_in[1];
  const float* h0   = (const float*)d_in[2];
  const float* c0   = (const float*)d_in[3];
  const float* w1   = (const float*)d_in[4];
  const float* b1   = (const float*)d_in[5];
  const float* w2   = (const float*)d_in[6];
  const float* b2   = (const float*)d_in[7];
  const float* w3   = (const float*)d_in[8];
  const float* b3   = (const float*)d_in[9];
  const float* fcw  = (const float*)d_in[10];
  const float* fcb  = (const float*)d_in[11];
  const float* wi   = (const float*)d_in[12];
  const float* wh   = (const float*)d_in[13];
  const float* bi   = (const float*)d_in[14];
  const float* bh   = (const float*)d_in[15];
  const float* aw   = (const float*)d_in[16];
  const float* abv  = (const float*)d_in[17];
  const float* cw   = (const float*)d_in[18];
  const float* cbv  = (const float*)d_in[19];
  float* out = (float*)d_out;

  const size_t SZ_A1 = 29491200, SZ_A2 = 9437184, SZ_A3 = 4194304;
  const size_t SZ_F = 2097152, SZ_G = 4194304, SZ_O = 1048576;
  const size_t SZ_WHT = 262144;
  const size_t need =
      (SZ_A1 + SZ_A2 + SZ_A3 + SZ_F + SZ_G + SZ_O + SZ_WHT) * 4;
  if (ws_size < need) return;

  float* wsp  = (float*)d_ws;
  float* a1   = wsp;
  float* a2   = a1 + SZ_A1;
  float* a3   = a2 + SZ_A2;
  float* feats= a3 + SZ_A3;
  float* gts  = feats + SZ_F;
  float* outs = gts + SZ_G;
  float* whT  = outs + SZ_O;

  conv1_kernel<<<4096, 256, 0, stream>>>(x, w1, b1, a1);
  conv2_kernel<<<4096, 192, 0, stream>>>(a1, w2, b2, a2);
  conv3_kernel<<<4096, 256, 0, stream>>>(a2, w3, b3, a3);
  gemm_bias_kernel<<<dim3(8, 64), 256, 0, stream>>>(a3, fcw, fcb, nullptr, feats,
                                                    4096, 512, 1024, 1);
  gemm_bias_kernel<<<dim3(16, 64), 256, 0, stream>>>(feats, wi, bi, bh, gts,
                                                     4096, 1024, 512, 0);
  transpose_wh_kernel<<<dim3(32, 8), 256, 0, stream>>>(wh, whT);
  lstm_env_kernel<<<32, 512, 0, stream>>>(gts, whT, done, h0, c0, outs);
  heads_kernel<<<512, 256, 0, stream>>>(outs, aw, abv, cw, cbv, out);
}

// Round 5
// 1921.370 us; speedup vs baseline: 1.8437x; 1.7388x over previous
//
#include <hip/hip_runtime.h>
#include <math.h>

// ---------------------------------------------------------------------------
// Shapes: T=128, N=32 -> TN=4096
//  x: (4096,4,64,64) f32 | conv1 (32,4,8,8)s4 -> a1 (4096,32,15,15)
//  conv2 (64,32,4,4)s2 -> a2 (4096,64,6,6) | conv3 (64,64,3,3)s1 -> a3 (4096,1024)
//  fc (512,1024) -> feats (4096,512) | lstm wi(1024,512) wh(1024,256) H=256
//  heads: actor(18,256) critic(1,256) -> out (4096,19)
// ---------------------------------------------------------------------------

typedef _Float16 half2_t __attribute__((ext_vector_type(2)));

__device__ inline float dot8(float4 a, float4 b, float4 wa, float4 wb, float s) {
  s = fmaf(a.x, wa.x, s); s = fmaf(a.y, wa.y, s);
  s = fmaf(a.z, wa.z, s); s = fmaf(a.w, wa.w, s);
  s = fmaf(b.x, wb.x, s); s = fmaf(b.y, wb.y, s);
  s = fmaf(b.z, wb.z, s); s = fmaf(b.w, wb.w, s);
  return s;
}

// ---- conv1 v3: block = frame; x staged one channel at a time into LDS ----
__global__ __launch_bounds__(256) void conv1_kernel(
    const float* __restrict__ x, const float* __restrict__ w,
    const float* __restrict__ bias, float* __restrict__ out) {
  __shared__ float xs[64 * 68];      // 17408 B, one input channel
  const int n = blockIdx.x;
  const int t = threadIdx.x;
  const int oy = t >> 4;             // 0..15 (15 idle in compute)
  const int og = t & 15;
  const int oc0 = og * 2;

  float acc[15][2] = {};
  const float4* xg = (const float4*)(x + (size_t)n * 16384);
  const float* wb = w + oc0 * 256;   // oc stride 4*8*8=256

  for (int c = 0; c < 4; ++c) {
    __syncthreads();                 // previous channel consumed
    #pragma unroll
    for (int i = 0; i < 4; ++i) {    // stage 1024 float4
      int f4 = i * 256 + t;
      int y = f4 >> 4, xq = f4 & 15;
      *(float4*)&xs[y * 68 + xq * 4] = xg[c * 1024 + f4];
    }
    __syncthreads();
    if (oy < 15) {
      for (int ky = 0; ky < 8; ++ky) {
        const float* xr = &xs[(4 * oy + ky) * 68];
        const float* wr = wb + c * 64 + ky * 8;
        const float4 w00 = *(const float4*)(wr);
        const float4 w01 = *(const float4*)(wr + 4);
        const float4 w10 = *(const float4*)(wr + 256);
        const float4 w11 = *(const float4*)(wr + 260);
        {
          float4 xv[9];
          #pragma unroll
          for (int i = 0; i < 9; ++i) xv[i] = *(const float4*)(xr + 4 * i);
          #pragma unroll
          for (int p = 0; p < 8; ++p) {
            acc[p][0] = dot8(xv[p], xv[p + 1], w00, w01, acc[p][0]);
            acc[p][1] = dot8(xv[p], xv[p + 1], w10, w11, acc[p][1]);
          }
        }
        {
          float4 yv[8];
          #pragma unroll
          for (int i = 0; i < 8; ++i) yv[i] = *(const float4*)(xr + 32 + 4 * i);
          #pragma unroll
          for (int p = 8; p < 15; ++p) {
            acc[p][0] = dot8(yv[p - 8], yv[p - 7], w00, w01, acc[p][0]);
            acc[p][1] = dot8(yv[p - 8], yv[p - 7], w10, w11, acc[p][1]);
          }
        }
      }
    }
  }
  if (oy < 15) {
    const float inv = 1.f / 255.f;
    #pragma unroll
    for (int o = 0; o < 2; ++o) {
      const int oc = oc0 + o;
      const float bb = bias[oc];
      float* orow = out + ((size_t)n * 32 + oc) * 225 + oy * 15;
      #pragma unroll
      for (int p = 0; p < 15; ++p)
        orow[p] = fmaxf(fmaf(acc[p][o], inv, bb), 0.f);
    }
  }
}

// ---- conv2 v3: block = frame (192 thr); a1 frame staged in LDS ----
__global__ __launch_bounds__(192) void conv2_kernel(
    const float* __restrict__ a1, const float* __restrict__ w,
    const float* __restrict__ bias, float* __restrict__ out) {
  __shared__ float xs[32 * 15 * 16];   // 30720 B
  const int n = blockIdx.x;
  const int t = threadIdx.x;           // 0..191
  const float* ag = a1 + (size_t)n * 7200;
  for (int i = 0; i < 38; ++i) {
    int idx = i * 192 + t;
    if (idx < 7200) {
      int c = idx / 225, rem = idx - c * 225;
      int row = rem / 15, col = rem - row * 15;
      xs[(c * 15 + row) * 16 + col] = ag[idx];
    }
  }
  __syncthreads();

  const int oy = t >> 5;               // 0..5
  const int op = t & 31;
  const int oc0 = op * 2;
  float acc[6][2] = {};
  const float* wb = w + oc0 * 512;     // oc stride 32*4*4=512

  for (int c = 0; c < 32; ++c) {
    #pragma unroll
    for (int ky = 0; ky < 4; ++ky) {
      const float* xr = &xs[(c * 15 + 2 * oy + ky) * 16];
      const float4 xa = *(const float4*)(xr);
      const float4 xb = *(const float4*)(xr + 4);
      const float4 xc = *(const float4*)(xr + 8);
      const float2 xd = *(const float2*)(xr + 12);
      const float xv[14] = {xa.x, xa.y, xa.z, xa.w, xb.x, xb.y, xb.z, xb.w,
                            xc.x, xc.y, xc.z, xc.w, xd.x, xd.y};
      const float* wr = wb + c * 16 + ky * 4;
      const float4 w0 = *(const float4*)(wr);
      const float4 w1 = *(const float4*)(wr + 512);
      #pragma unroll
      for (int p = 0; p < 6; ++p) {
        const int b = 2 * p;
        float s0 = acc[p][0], s1 = acc[p][1];
        s0 = fmaf(xv[b], w0.x, s0);     s1 = fmaf(xv[b], w1.x, s1);
        s0 = fmaf(xv[b + 1], w0.y, s0); s1 = fmaf(xv[b + 1], w1.y, s1);
        s0 = fmaf(xv[b + 2], w0.z, s0); s1 = fmaf(xv[b + 2], w1.z, s1);
        s0 = fmaf(xv[b + 3], w0.w, s0); s1 = fmaf(xv[b + 3], w1.w, s1);
        acc[p][0] = s0; acc[p][1] = s1;
      }
    }
  }
  #pragma unroll
  for (int o = 0; o < 2; ++o) {
    const int oc = oc0 + o;
    const float bb = bias[oc];
    float* orow = out + ((size_t)n * 64 + oc) * 36 + oy * 6;
    #pragma unroll
    for (int p = 0; p < 6; ++p)
      orow[p] = fmaxf(acc[p][o] + bb, 0.f);
  }
}

// ---- conv3 v3: block = frame; x frame AND transposed weights in LDS ----
__global__ __launch_bounds__(256) void conv3_kernel(
    const float* __restrict__ a2, const float* __restrict__ w,
    const float* __restrict__ bias, float* __restrict__ out) {
  __shared__ float wTs[144 * 65];      // 37440 B
  __shared__ float xs2[64 * 36];       // 9216 B
  const int n = blockIdx.x;
  const int t = threadIdx.x;
  const int oy = t >> 6;               // 0..3
  const int oc = t & 63;

  const float* ab = a2 + (size_t)n * 2304;
  #pragma unroll
  for (int i = 0; i < 9; ++i) xs2[i * 256 + t] = ab[i * 256 + t];

  float acc[4] = {};
  for (int c0 = 0; c0 < 64; c0 += 16) {
    __syncthreads();
    #pragma unroll
    for (int i = 0; i < 36; ++i) {
      const int lin = i * 256 + t;
      const int ocs = lin / 144;
      const int rem = lin - ocs * 144;
      wTs[rem * 65 + ocs] = w[(size_t)ocs * 576 + c0 * 9 + rem];
    }
    __syncthreads();
    for (int cc = 0; cc < 16; ++cc) {
      const float* xb = &xs2[(c0 + cc) * 36];
      #pragma unroll
      for (int ky = 0; ky < 3; ++ky) {
        const float* xr = xb + (oy + ky) * 6;
        const float2 x01 = *(const float2*)(xr);
        const float2 x23 = *(const float2*)(xr + 2);
        const float2 x45 = *(const float2*)(xr + 4);
        const float xv[6] = {x01.x, x01.y, x23.x, x23.y, x45.x, x45.y};
        const float* wrow = &wTs[(cc * 9 + ky * 3) * 65 + oc];
        const float wk0 = wrow[0], wk1 = wrow[65], wk2 = wrow[130];
        #pragma unroll
        for (int p = 0; p < 4; ++p)
          acc[p] = fmaf(xv[p], wk0,
                   fmaf(xv[p + 1], wk1,
                   fmaf(xv[p + 2], wk2, acc[p])));
      }
    }
  }
  const float bb = bias[oc];
  float* orow = out + ((size_t)n * 64 + oc) * 16 + oy * 4;
  #pragma unroll
  for (int p = 0; p < 4; ++p)
    orow[p] = fmaxf(acc[p] + bb, 0.f);
}

// ---- generic GEMM: C[M,N] = act(A[M,K] @ B[N,K]^T + bias1 (+bias2)) ----
__global__ __launch_bounds__(256) void gemm_bias_kernel(
    const float* __restrict__ A, const float* __restrict__ B,
    const float* __restrict__ bias1, const float* __restrict__ bias2,
    float* __restrict__ C, int M, int N, int K, int relu) {
  __shared__ float As[16][68];
  __shared__ float Bs[16][68];
  const int t = threadIdx.x;
  const int n0 = blockIdx.x * 64;
  const int m0 = blockIdx.y * 64;
  const int ty = t >> 4, tx = t & 15;
  const int sl = t >> 2, kq = (t & 3) * 4;

  float acc[4][4] = {};

  for (int k0 = 0; k0 < K; k0 += 16) {
    float4 av = *(const float4*)(A + (size_t)(m0 + sl) * K + k0 + kq);
    float4 bv = *(const float4*)(B + (size_t)(n0 + sl) * K + k0 + kq);
    As[kq + 0][sl] = av.x; As[kq + 1][sl] = av.y;
    As[kq + 2][sl] = av.z; As[kq + 3][sl] = av.w;
    Bs[kq + 0][sl] = bv.x; Bs[kq + 1][sl] = bv.y;
    Bs[kq + 2][sl] = bv.z; Bs[kq + 3][sl] = bv.w;
    __syncthreads();
    #pragma unroll
    for (int kk = 0; kk < 16; ++kk) {
      float4 a = *(const float4*)&As[kk][ty * 4];
      float4 b = *(const float4*)&Bs[kk][tx * 4];
      float ar[4] = {a.x, a.y, a.z, a.w};
      float br[4] = {b.x, b.y, b.z, b.w};
      #pragma unroll
      for (int i = 0; i < 4; ++i)
        #pragma unroll
        for (int j = 0; j < 4; ++j)
          acc[i][j] = fmaf(ar[i], br[j], acc[i][j]);
    }
    __syncthreads();
  }

  #pragma unroll
  for (int i = 0; i < 4; ++i) {
    int m = m0 + ty * 4 + i;
    #pragma unroll
    for (int j = 0; j < 4; ++j) {
      int n = n0 + tx * 4 + j;
      float v = acc[i][j] + bias1[n];
      if (bias2) v += bias2[n];
      if (relu) v = fmaxf(v, 0.f);
      C[(size_t)m * N + n] = v;
    }
  }
}

// ---- wh -> fp16 packed k-major: whP[k2*1024 + r] = (wh[r][2k2], wh[r][2k2+1])
__global__ __launch_bounds__(256) void convert_wh_kernel(
    const float* __restrict__ wh, half2_t* __restrict__ whP) {
  __shared__ float ws[32][257];        // padded: conflict-free column reads
  const int b = blockIdx.x;            // row block, 32 rows
  const int t = threadIdx.x;
  for (int i = 0; i < 32; ++i) {
    int lin = i * 256 + t;
    int rr = lin >> 8, k = lin & 255;
    ws[rr][k] = wh[(size_t)(b * 32 + rr) * 256 + k];
  }
  __syncthreads();
  const int rr = t & 31, k2g = t >> 5;
  for (int i = 0; i < 16; ++i) {
    int k2 = k2g * 16 + i;
    half2_t h;
    h.x = (_Float16)ws[rr][2 * k2];
    h.y = (_Float16)ws[rr][2 * k2 + 1];
    whP[(size_t)k2 * 1024 + b * 32 + rr] = h;
  }
}

// ---- LSTM v3: block = one env, 1024 threads (16 waves on one CU).
// Thread t: rows r0=4*(t&255)..+3, k2 slice ks=t>>8 (32 k2 each).
// Per iter: one 16B coalesced fp16 weight load + 4 v_dot2_f32_f16 (fp32 acc).
// Partials reduced via float4 LDS tile (conflict-free both directions).
__global__ __launch_bounds__(1024) void lstm_env_kernel(
    const float* __restrict__ gates_pre, const half2_t* __restrict__ whP,
    const float* __restrict__ done, const float* __restrict__ h0,
    const float* __restrict__ c0, float* __restrict__ outs) {
  __shared__ float h_s[256];
  __shared__ float c_s[256];
  __shared__ half2_t h2_s[128];
  __shared__ float4 red4[4 * 256];     // [ks][rq] -> flat float = ks*1024 + r
  __shared__ float gb[1024];
  const int e = blockIdx.x;            // env 0..31
  const int t = threadIdx.x;           // 0..1023
  const int rq = t & 255;
  const int ks = t >> 8;               // 0..3 (wave-uniform)
  const int r0 = rq * 4;

  if (t < 256) { h_s[t] = h0[e * 256 + t]; c_s[t] = c0[e * 256 + t]; }
  __syncthreads();

  for (int st = 0; st < 128; ++st) {
    const float m = 1.f - done[st * 32 + e];
    if (t < 128) {                     // mask h, build fp16 copy
      float ha = h_s[2 * t] * m, hb = h_s[2 * t + 1] * m;
      h_s[2 * t] = ha; h_s[2 * t + 1] = hb;
      half2_t hh; hh.x = (_Float16)ha; hh.y = (_Float16)hb;
      h2_s[t] = hh;
    } else if (t >= 256 && t < 512) {
      c_s[t - 256] *= m;
    }
    const float gp = gates_pre[(size_t)(st * 32 + e) * 1024 + t];  // prefetch
    __syncthreads();

    float a0 = 0.f, a1 = 0.f, a2 = 0.f, a3 = 0.f;
    const half2_t* wp = whP + (size_t)(ks * 32) * 1024 + r0;
    #pragma unroll 8
    for (int i = 0; i < 32; ++i) {
      const half2_t hk = h2_s[ks * 32 + i];            // broadcast
      const float4 wraw = *(const float4*)(wp + (size_t)i * 1024);
      a0 = __builtin_amdgcn_fdot2(hk, __builtin_bit_cast(half2_t, wraw.x), a0, false);
      a1 = __builtin_amdgcn_fdot2(hk, __builtin_bit_cast(half2_t, wraw.y), a1, false);
      a2 = __builtin_amdgcn_fdot2(hk, __builtin_bit_cast(half2_t, wraw.z), a2, false);
      a3 = __builtin_amdgcn_fdot2(hk, __builtin_bit_cast(half2_t, wraw.w), a3, false);
    }
    red4[ks * 256 + rq] = make_float4(a0, a1, a2, a3); // ds_write_b128, seq
    __syncthreads();

    {                                  // finalize gate row t
      const float* red = (const float*)red4;
      gb[t] = red[t] + red[1024 + t] + red[2048 + t] + red[3072 + t] + gp;
    }
    __syncthreads();

    if (t < 256) {
      float iv = gb[t], fv = gb[256 + t], gv = gb[512 + t], ov = gb[768 + t];
      float ig = 1.f / (1.f + expf(-iv));
      float fg = 1.f / (1.f + expf(-fv));
      float og = 1.f / (1.f + expf(-ov));
      float cn = fmaf(fg, c_s[t], ig * tanhf(gv));
      float hn = og * tanhf(cn);
      c_s[t] = cn;
      h_s[t] = hn;
      outs[(size_t)st * 8192 + e * 256 + t] = hn;
    }
    __syncthreads();
  }
}

// ---- heads ----
__global__ __launch_bounds__(256) void heads_kernel(
    const float* __restrict__ outs, const float* __restrict__ aw,
    const float* __restrict__ ab, const float* __restrict__ cw,
    const float* __restrict__ cb, float* __restrict__ out) {
  __shared__ float rs[8 * 256];
  const int t = threadIdx.x;
  const int r0 = blockIdx.x * 8;
  for (int i = 0; i < 8; ++i)
    rs[i * 256 + t] = outs[(size_t)(r0 + i) * 256 + t];
  __syncthreads();
  int r = t >> 5, c = t & 31;
  if (c < 19) {
    const float* wr = (c < 18) ? (aw + c * 256) : cw;
    float bias = (c < 18) ? ab[c] : cb[0];
    float acc = 0.f;
    for (int k = 0; k < 256; ++k) acc = fmaf(rs[r * 256 + k], wr[k], acc);
    out[(size_t)(r0 + r) * 19 + c] = acc + bias;
  }
}

extern "C" void kernel_launch(void* const* d_in, const int* in_sizes, int n_in,
                              void* d_out, int out_size, void* d_ws, size_t ws_size,
                              hipStream_t stream) {
  (void)in_sizes; (void)n_in; (void)out_size;
  const float* x    = (const float*)d_in[0];
  const float* done = (const float*)d_in[1];
  const float* h0   = (const float*)d_in[2];
  const float* c0   = (const float*)d_in[3];
  const float* w1   = (const float*)d_in[4];
  const float* b1   = (const float*)d_in[5];
  const float* w2   = (const float*)d_in[6];
  const float* b2   = (const float*)d_in[7];
  const float* w3   = (const float*)d_in[8];
  const float* b3   = (const float*)d_in[9];
  const float* fcw  = (const float*)d_in[10];
  const float* fcb  = (const float*)d_in[11];
  const float* wi   = (const float*)d_in[12];
  const float* wh   = (const float*)d_in[13];
  const float* bi   = (const float*)d_in[14];
  const float* bh   = (const float*)d_in[15];
  const float* aw   = (const float*)d_in[16];
  const float* abv  = (const float*)d_in[17];
  const float* cw   = (const float*)d_in[18];
  const float* cbv  = (const float*)d_in[19];
  float* out = (float*)d_out;

  const size_t SZ_A1 = 29491200, SZ_A2 = 9437184, SZ_A3 = 4194304;
  const size_t SZ_F = 2097152, SZ_G = 4194304, SZ_O = 1048576;
  const size_t SZ_WHP = 131072;        // 512 KB fp16 packed Wh (in floats)
  const size_t need =
      (SZ_A1 + SZ_A2 + SZ_A3 + SZ_F + SZ_G + SZ_O + SZ_WHP) * 4;
  if (ws_size < need) return;

  float* wsp  = (float*)d_ws;
  float* a1   = wsp;
  float* a2   = a1 + SZ_A1;
  float* a3   = a2 + SZ_A2;
  float* feats= a3 + SZ_A3;
  float* gts  = feats + SZ_F;
  float* outs = gts + SZ_G;
  half2_t* whP = (half2_t*)(outs + SZ_O);

  conv1_kernel<<<4096, 256, 0, stream>>>(x, w1, b1, a1);
  conv2_kernel<<<4096, 192, 0, stream>>>(a1, w2, b2, a2);
  conv3_kernel<<<4096, 256, 0, stream>>>(a2, w3, b3, a3);
  gemm_bias_kernel<<<dim3(8, 64), 256, 0, stream>>>(a3, fcw, fcb, nullptr, feats,
                                                    4096, 512, 1024, 1);
  gemm_bias_kernel<<<dim3(16, 64), 256, 0, stream>>>(feats, wi, bi, bh, gts,
                                                     4096, 1024, 512, 0);
  convert_wh_kernel<<<32, 256, 0, stream>>>(wh, whP);
  lstm_env_kernel<<<32, 1024, 0, stream>>>(gts, whP, done, h0, c0, outs);
  heads_kernel<<<512, 256, 0, stream>>>(outs, aw, abv, cw, cbv, out);
}